// Round 1
// baseline (178.956 us; speedup 1.0000x reference)
//
#include <hip/hip_runtime.h>

// Problem: x_final[k] = mean(replicates[k,:]) * (1 - 0.8^100)  (closed form of
// the 100-step SGD: x <- 0.8 x + 0.2 m). Reduces to a 64x500000 fp32 row-mean.
// Memory-bound: 128 MB read, roofline ~20 us @ 6.3 TB/s.

#define ROWS 64
#define COLS 500000
#define VEC4 (COLS / 4)          // 125000 float4 per row; row base is 16B-aligned
#define BLOCKS_PER_ROW 32
#define THREADS 256

__global__ __launch_bounds__(THREADS)
void row_partial_sum(const float* __restrict__ in, double* __restrict__ partial) {
    const int row = blockIdx.y;
    const int seg = blockIdx.x;
    const float4* rp = reinterpret_cast<const float4*>(in + (size_t)row * COLS);

    double acc = 0.0;
    for (int i = seg * THREADS + threadIdx.x; i < VEC4; i += BLOCKS_PER_ROW * THREADS) {
        float4 v = rp[i];
        acc += (double)v.x + (double)v.y + (double)v.z + (double)v.w;
    }

    // wave-64 shuffle reduce
    #pragma unroll
    for (int off = 32; off > 0; off >>= 1)
        acc += __shfl_down(acc, off, 64);

    __shared__ double wsum[THREADS / 64];
    const int lane = threadIdx.x & 63;
    const int wave = threadIdx.x >> 6;
    if (lane == 0) wsum[wave] = acc;
    __syncthreads();
    if (threadIdx.x == 0) {
        double s = 0.0;
        #pragma unroll
        for (int w = 0; w < THREADS / 64; ++w) s += wsum[w];
        partial[row * BLOCKS_PER_ROW + seg] = s;  // deterministic: no atomics
    }
}

__global__ void finalize(const double* __restrict__ partial, float* __restrict__ out) {
    const int r = threadIdx.x;
    if (r < ROWS) {
        double s = 0.0;
        #pragma unroll
        for (int b = 0; b < BLOCKS_PER_ROW; ++b) s += partial[r * BLOCKS_PER_ROW + b];
        const double m = s / (double)COLS;
        double f = 1.0;
        #pragma unroll
        for (int t = 0; t < 100; ++t) f *= 0.8;   // 0.8^100 ~ 2.04e-10
        out[r] = (float)(m * (1.0 - f));
    }
}

extern "C" void kernel_launch(void* const* d_in, const int* in_sizes, int n_in,
                              void* d_out, int out_size, void* d_ws, size_t ws_size,
                              hipStream_t stream) {
    const float* in = (const float*)d_in[0];
    float* out = (float*)d_out;
    double* partial = (double*)d_ws;  // ROWS * BLOCKS_PER_ROW doubles = 16 KB

    dim3 grid(BLOCKS_PER_ROW, ROWS);
    hipLaunchKernelGGL(row_partial_sum, grid, dim3(THREADS), 0, stream, in, partial);
    hipLaunchKernelGGL(finalize, dim3(1), dim3(64), 0, stream, partial, out);
}